// Round 1
// baseline (2183.588 us; speedup 1.0000x reference)
//
#include <hip/hip_runtime.h>
#include <math.h>

#define NN    64
#define NXX   4096
#define NT    512
#define NCH   8          // elements per thread = NXX/NT
#define NITER 25
#define EPSQ  0.1
#define SREG  1e-9
#define BIGV  1e10

// ---- wave (64-lane) reductions -------------------------------------------
__device__ __forceinline__ double wsum(double v) {
#pragma unroll
  for (int m = 32; m > 0; m >>= 1) v += __shfl_xor(v, m, 64);
  return v;
}
__device__ __forceinline__ double wmin(double v) {
#pragma unroll
  for (int m = 32; m > 0; m >>= 1) v = fmin(v, __shfl_xor(v, m, 64));
  return v;
}

// One block per batch element. 512 threads = 8 waves.
// Element e = tid + 512*k  (k=0..7). grid row i = e>>6 = w + 8k, col j = lane.
__global__ __launch_bounds__(NT, 2)
void ipm_kernel(const float* __restrict__ xin, const float* __restrict__ gidin,
                const float* __restrict__ expin, float* __restrict__ outp)
{
  const int b    = blockIdx.x;
  const int tid  = threadIdx.x;
  const int lane = tid & 63;
  const int w    = tid >> 6;     // wave id 0..7

  // ---- LDS ----------------------------------------------------------------
  __shared__ double DnT[64][65];     // DnT[j][i] = invD(i,j)/sqrt(Rh_i)
  __shared__ double Mg[64][66];      // augmented reduced Schur [M | rhs_d | mw]
  __shared__ double cpA[8][64], cpB[8][64], cpC[8][64];  // column partials
  __shared__ double req1[64], req2[64], rhs1[64], rhs2v[64];
  __shared__ double Rhv[64], Ruv[64], ccv[64], wvv[64];
  __shared__ double usv[64], rsv[64], uvv[64], mw0[64];
  __shared__ double dav[64], ddv[64], h1v[64], h2v[64];
  __shared__ double yav[64], ydv[64];
  __shared__ double fvec[64], evec[64];
  __shared__ double wpA[8], wpB[8];
  __shared__ double scal[8];  // 0=mu 1=req3 2=q 3=rhs3 4=dt 5=alpha 6=yt 7=gsum

  // ---- constants f, e; init y --------------------------------------------
  if (tid < 64) {
    fvec[tid] = (double)gidin[tid];   // reference uses group_ids[0] for ALL batches
    evec[tid] = (double)expin[tid];
    yav[tid] = 0.0; ydv[tid] = 0.0;
  }
  if (tid == 0) scal[6] = 0.0;
  __syncthreads();
  if (tid == 0) {
    double gs = 0.0;
    for (int i = 0; i < 64; ++i) gs += fvec[i];
    scal[7] = gs;
  }
  __syncthreads();
  if (tid < 64) {
    double g = fvec[tid], gs = scal[7];
    fvec[tid] = g / gs - (1.0 - g) / (64.0 - gs);
  }
  __syncthreads();

  // ---- per-thread state ---------------------------------------------------
  double p[NCH], z[NCH], s1[NCH], s2[NCH], l1[NCH], l2[NCH];
  double fr[NCH], fe[NCH];
  const double ev = evec[lane];
#pragma unroll
  for (int k = 0; k < NCH; ++k) {
    int e = tid + NT * k;
    p[k]  = (double)xin[(size_t)b * NXX + e];
    z[k] = 0.0; s1[k] = 1.0; s2[k] = 1.0; l1[k] = 1.0; l2[k] = 1.0;
    fr[k] = fvec[w + 8 * k];
    fe[k] = fr[k] * ev;
  }

  // ======================= main IPM loop ==================================
  for (int iter = 0; iter < NITER; ++iter) {
    // ---- Phase A: r_eq pieces + mu partials ------------------------------
    double cz = 0.0, fz = 0.0, msl = 0.0;
#pragma unroll
    for (int k = 0; k < NCH; ++k) {
      double rsum = wsum(z[k]);
      if (lane == 0) req1[w + 8 * k] = rsum - 1.0;
      cz  += z[k];
      fz  += fe[k] * z[k];
      msl += s1[k] * l1[k] + s2[k] * l2[k];
    }
    cpA[w][lane] = cz;
    {
      double a = wsum(fz), c = wsum(msl);
      if (lane == 0) { wpA[w] = a; wpB[w] = c; }
    }
    __syncthreads();
    // ---- Phase B: finalize col sums of z, mu, req3 -----------------------
    if (tid < 64) {
      double s = 0.0;
      for (int q = 0; q < 8; ++q) s += cpA[q][tid];
      req2[tid] = s - 1.0;
    }
    if (tid == 0) {
      double a = 0.0, c = 0.0;
      for (int q = 0; q < 8; ++q) { a += wpA[q]; c += wpB[q]; }
      scal[1] = a;              // req3 (fair residual)
      scal[0] = c / 8192.0;     // mu
    }
    __syncthreads();

    // ---- Phase C: invD, rhs_z, all first-order reductions ----------------
    const double mu01 = 0.1 * scal[0];
    const double yt   = scal[6];
    double dinv[NCH], rz[NCH];
    double cD = 0.0, cfD = 0.0, cg = 0.0, qac = 0.0, fgac = 0.0;
#pragma unroll
    for (int k = 0; k < NCH; ++k) {
      int i = w + 8 * k;
      double is1 = 1.0 / s1[k], is2 = 1.0 / s2[k];
      double D = 1.0 / (EPSQ + l1[k] * is1 + l2[k] * is2);
      dinv[k] = D;
      double rd  = EPSQ * z[k] + p[k] + (yav[i] + ydv[lane] + yt * fe[k]) + (l2[k] - l1[k]);
      double tt1 = (mu01 - l1[k] * z[k]) * is1;
      double tt2 = (l2[k] * (z[k] - 1.0) + mu01) * is2;
      double r = -(rd - tt1 + tt2);
      rz[k] = r;
      double g = r * D;
      double sD  = wsum(D);
      double sED = wsum(ev * D);
      double sg  = wsum(g);
      if (lane == 0) {
        Rhv[i]  = sD + SREG;
        Ruv[i]  = sED;
        rhs1[i] = sg + req1[i];
      }
      cD  += D;  cfD += fr[k] * D;  cg += g;
      qac += fe[k] * fe[k] * D;
      fgac += fe[k] * g;
    }
    cpA[w][lane] = cD; cpB[w][lane] = cfD; cpC[w][lane] = cg;
    {
      double a = wsum(qac), c = wsum(fgac);
      if (lane == 0) { wpA[w] = a; wpB[w] = c; }
    }
    __syncthreads();

    // ---- Phase D: finalize col sums, border vectors, write DnT -----------
    if (tid < 64) {
      double a = 0.0, c = 0.0, d = 0.0;
      for (int q = 0; q < 8; ++q) { a += cpA[q][tid]; c += cpB[q][tid]; d += cpC[q][tid]; }
      ccv[tid]   = a;                 // colsum(invD)
      wvv[tid]   = evec[tid] * c;     // w_j
      rhs2v[tid] = d + req2[tid];
      double ir  = 1.0 / sqrt(Rhv[tid]);
      double u   = fvec[tid] * Ruv[tid];
      uvv[tid] = u;
      usv[tid] = u * ir;
      rsv[tid] = rhs1[tid] * ir;
    }
    if (tid == 0) {
      double a = 0.0, c = 0.0;
      for (int q = 0; q < 8; ++q) { a += wpA[q]; c += wpB[q]; }
      scal[2] = a;             // q
      scal[3] = c + scal[1];   // rhs3
    }
#pragma unroll
    for (int k = 0; k < NCH; ++k) {
      int i = w + 8 * k;
      DnT[lane][i] = dinv[k] / sqrt(Rhv[i]);
    }
    __syncthreads();

    // ---- Phase E: build augmented reduced Schur Mg = [M | rhs_d | mw] ----
    {
      int j = tid >> 3, c0 = tid & 7;
#pragma unroll 1
      for (int m = 0; m < 9; ++m) {
        int l = c0 + 8 * m;
        if (l < 64) {
          double acc = 0.0;
#pragma unroll 8
          for (int i = 0; i < 64; ++i) acc += DnT[j][i] * DnT[l][i];
          Mg[j][l] = ((j == l) ? (ccv[j] + SREG) : 0.0) - acc;
        } else if (l == 64) {
          double acc = 0.0;
#pragma unroll 8
          for (int i = 0; i < 64; ++i) acc += DnT[j][i] * rsv[i];
          Mg[j][64] = rhs2v[j] - acc;
        } else if (l == 65) {
          double acc = 0.0;
#pragma unroll 8
          for (int i = 0; i < 64; ++i) acc += DnT[j][i] * usv[i];
          double vv = wvv[j] - acc;
          Mg[j][65] = vv;
          mw0[j] = vv;
        }
      }
    }
    __syncthreads();

    // ---- Phase F: forward Gaussian elimination (no pivoting, SPD) --------
    {
      int j = tid >> 3, c0 = tid & 7;
#pragma unroll 1
      for (int k = 0; k < 63; ++k) {
        if (j > k) {
          double ipiv = 1.0 / Mg[k][k];
          double mult = Mg[j][k] * ipiv;
#pragma unroll
          for (int m = 0; m < 9; ++m) {
            int l = c0 + 8 * m;
            if (l < 66 && l > k) Mg[j][l] -= mult * Mg[k][l];
          }
        }
        __syncthreads();
      }
    }

    // ---- Phase G: back elimination on the two augmented columns ----------
#pragma unroll 1
    for (int k = 63; k >= 1; --k) {
      if (tid < 128) {
        int j = tid & 63, c = 64 + (tid >> 6);
        if (j < k) {
          double xk = Mg[k][c] / Mg[k][k];
          Mg[j][c] -= Mg[j][k] * xk;
        }
      }
      __syncthreads();
    }
    if (tid < 64) {
      h1v[tid] = Mg[tid][64] / Mg[tid][tid];
      h2v[tid] = Mg[tid][65] / Mg[tid][tid];
    }
    __syncthreads();

    // ---- Phase H: fairness border solve (wave 0 only) --------------------
    if (w == 0) {
      double a1 = wsum(usv[lane] * usv[lane]);
      double a2 = wsum(usv[lane] * rsv[lane]);
      double a3 = wsum(mw0[lane] * h1v[lane]);
      double a4 = wsum(mw0[lane] * h2v[lane]);
      double qp  = scal[2] + SREG - a1;
      double r3p = scal[3] - a2;
      double tloc = (r3p - a3) / (qp - a4);
      ddv[lane] = h1v[lane] - tloc * h2v[lane];
      if (lane == 0) scal[4] = tloc;
    }
    __syncthreads();

    // ---- da (row duals) ---------------------------------------------------
    const double tf = scal[4];
#pragma unroll
    for (int k = 0; k < NCH; ++k) {
      int i = w + 8 * k;
      double rdot = wsum(dinv[k] * ddv[lane]);
      if (lane == 0) dav[i] = (rhs1[i] - rdot - uvv[i] * tf) / Rhv[i];
    }
    __syncthreads();

    // ---- Phase I: dz/ds/dlam, alpha, update ------------------------------
    double amin = BIGV;
    double dz[NCH];
#pragma unroll
    for (int k = 0; k < NCH; ++k) {
      int i = w + 8 * k;
      double dyA = dav[i] + ddv[lane] + tf * fe[k];
      double d   = (rz[k] - dyA) * dinv[k];
      dz[k] = d;
      double ri1 = s1[k] - z[k];
      double ri2 = z[k] + s2[k] - 1.0;
      double ds1 = d - ri1;
      double ds2 = -ri2 - d;
      double rc1 = l1[k] * s1[k] - mu01;
      double rc2 = l2[k] * s2[k] - mu01;
      double dl1 = (-rc1 - l1[k] * ds1) / s1[k];
      double dl2 = (-rc2 - l2[k] * ds2) / s2[k];
      if (ds1 < 0.0) amin = fmin(amin, -s1[k] / ds1);
      if (ds2 < 0.0) amin = fmin(amin, -s2[k] / ds2);
      if (dl1 < 0.0) amin = fmin(amin, -l1[k] / dl1);
      if (dl2 < 0.0) amin = fmin(amin, -l2[k] / dl2);
    }
    amin = wmin(amin);
    if (lane == 0) wpA[w] = amin;
    __syncthreads();
    if (tid == 0) {
      double a = wpA[0];
      for (int q = 1; q < 8; ++q) a = fmin(a, wpA[q]);
      scal[5] = fmin(1.0, 0.99 * a);
    }
    __syncthreads();
    const double al = scal[5];
#pragma unroll
    for (int k = 0; k < NCH; ++k) {
      double d   = dz[k];
      double ri1 = s1[k] - z[k];
      double ri2 = z[k] + s2[k] - 1.0;
      double ds1 = d - ri1;
      double ds2 = -ri2 - d;
      double rc1 = l1[k] * s1[k] - mu01;
      double rc2 = l2[k] * s2[k] - mu01;
      double dl1 = (-rc1 - l1[k] * ds1) / s1[k];
      double dl2 = (-rc2 - l2[k] * ds2) / s2[k];
      z[k]  += al * d;
      s1[k] += al * ds1;
      s2[k] += al * ds2;
      l1[k] += al * dl1;
      l2[k] += al * dl2;
    }
    if (tid < 64) {
      yav[tid] += al * dav[tid];
      ydv[tid] += al * ddv[tid];
    }
    if (tid == 0) scal[6] += al * scal[4];
    __syncthreads();
  }

  // ---- output (fp32) ------------------------------------------------------
#pragma unroll
  for (int k = 0; k < NCH; ++k) {
    int e = tid + NT * k;
    outp[(size_t)b * NXX + e] = (float)z[k];
  }
}

extern "C" void kernel_launch(void* const* d_in, const int* in_sizes, int n_in,
                              void* d_out, int out_size, void* d_ws, size_t ws_size,
                              hipStream_t stream)
{
  const float* x   = (const float*)d_in[0];
  const float* gid = (const float*)d_in[1];
  const float* ex  = (const float*)d_in[2];
  float* out = (float*)d_out;
  int nb = in_sizes[0] / NXX;   // 32 batches
  hipLaunchKernelGGL(ipm_kernel, dim3(nb), dim3(NT), 0, stream, x, gid, ex, out);
}

// Round 2
// 1575.417 us; speedup vs baseline: 1.3860x; 1.3860x over previous
//
#include <hip/hip_runtime.h>
#include <math.h>

#define NN    64
#define NXX   4096
#define NT    512
#define NCH   8          // elements per thread = NXX/NT
#define NITER 25
#define EPSQ  0.1
#define SREG  1e-9
#define BIGV  1e10

// ---- wave (64-lane) reductions -------------------------------------------
__device__ __forceinline__ double wsum(double v) {
#pragma unroll
  for (int m = 32; m > 0; m >>= 1) v += __shfl_xor(v, m, 64);
  return v;
}
__device__ __forceinline__ double wmin(double v) {
#pragma unroll
  for (int m = 32; m > 0; m >>= 1) v = fmin(v, __shfl_xor(v, m, 64));
  return v;
}

// One block per batch element. 512 threads = 8 waves.
// Element e = tid + 512*k  (k=0..7). grid row i = e>>6 = w + 8k, col j = lane.
__global__ __launch_bounds__(NT, 2)
void ipm_kernel(const float* __restrict__ xin, const float* __restrict__ gidin,
                const float* __restrict__ expin, float* __restrict__ outp)
{
  const int b    = blockIdx.x;
  const int tid  = threadIdx.x;
  const int lane = tid & 63;
  const int w    = tid >> 6;     // wave id 0..7

  // ---- LDS ----------------------------------------------------------------
  __shared__ double DnT[64][65];     // DnT[j][i] = invD(i,j)/sqrt(Rh_i)
  __shared__ double Mg[64][67];      // augmented reduced Schur [M | rhs_d | mw] (cols 0..65, pad)
  __shared__ double Pbuf[16][52];    // B^{-1} * panel-rest rows
  __shared__ double Binv[16][18];    // 16x16 pivot-block inverse
  __shared__ double cpA[8][64], cpB[8][64], cpC[8][64];  // column partials
  __shared__ double req1[64], req2[64], rhs1[64], rhs2v[64];
  __shared__ double Rhv[64], Ruv[64], ccv[64], wvv[64];
  __shared__ double usv[64], rsv[64], uvv[64], mw0[64];
  __shared__ double dav[64], ddv[64];
  __shared__ double yav[64], ydv[64];
  __shared__ double fvec[64], evec[64];
  __shared__ double wpA[8], wpB[8];
  __shared__ double scal[8];  // 0=mu 1=req3 2=q 3=rhs3 4=dt 5=alpha 6=yt 7=gsum

  // ---- constants f, e; init y --------------------------------------------
  if (tid < 64) {
    fvec[tid] = (double)gidin[tid];   // reference uses group_ids[0] for ALL batches
    evec[tid] = (double)expin[tid];
    yav[tid] = 0.0; ydv[tid] = 0.0;
  }
  if (tid == 0) scal[6] = 0.0;
  __syncthreads();
  if (tid == 0) {
    double gs = 0.0;
    for (int i = 0; i < 64; ++i) gs += fvec[i];
    scal[7] = gs;
  }
  __syncthreads();
  if (tid < 64) {
    double g = fvec[tid], gs = scal[7];
    fvec[tid] = g / gs - (1.0 - g) / (64.0 - gs);
  }
  __syncthreads();

  // ---- per-thread state ---------------------------------------------------
  double p[NCH], z[NCH], s1[NCH], s2[NCH], l1[NCH], l2[NCH];
  double fr[NCH], fe[NCH];
  const double ev = evec[lane];
#pragma unroll
  for (int k = 0; k < NCH; ++k) {
    int e = tid + NT * k;
    p[k]  = (double)xin[(size_t)b * NXX + e];
    z[k] = 0.0; s1[k] = 1.0; s2[k] = 1.0; l1[k] = 1.0; l2[k] = 1.0;
    fr[k] = fvec[w + 8 * k];
    fe[k] = fr[k] * ev;
  }

  // ======================= main IPM loop ==================================
  for (int iter = 0; iter < NITER; ++iter) {
    // ---- Phase A: r_eq pieces + mu partials ------------------------------
    double cz = 0.0, fz = 0.0, msl = 0.0;
#pragma unroll
    for (int k = 0; k < NCH; ++k) {
      double rsum = wsum(z[k]);
      if (lane == 0) req1[w + 8 * k] = rsum - 1.0;
      cz  += z[k];
      fz  += fe[k] * z[k];
      msl += s1[k] * l1[k] + s2[k] * l2[k];
    }
    cpA[w][lane] = cz;
    {
      double a = wsum(fz), c = wsum(msl);
      if (lane == 0) { wpA[w] = a; wpB[w] = c; }
    }
    __syncthreads();
    // ---- Phase B: finalize col sums of z, mu, req3 -----------------------
    if (tid < 64) {
      double s = 0.0;
      for (int q = 0; q < 8; ++q) s += cpA[q][tid];
      req2[tid] = s - 1.0;
    }
    if (tid == 0) {
      double a = 0.0, c = 0.0;
      for (int q = 0; q < 8; ++q) { a += wpA[q]; c += wpB[q]; }
      scal[1] = a;              // req3 (fair residual)
      scal[0] = c / 8192.0;     // mu
    }
    __syncthreads();

    // ---- Phase C: invD, rhs_z, all first-order reductions ----------------
    const double mu01 = 0.1 * scal[0];
    const double yt   = scal[6];
    double dinv[NCH], rz[NCH];
    double cD = 0.0, cfD = 0.0, cg = 0.0, qac = 0.0, fgac = 0.0;
#pragma unroll
    for (int k = 0; k < NCH; ++k) {
      int i = w + 8 * k;
      double is1 = 1.0 / s1[k], is2 = 1.0 / s2[k];
      double D = 1.0 / (EPSQ + l1[k] * is1 + l2[k] * is2);
      dinv[k] = D;
      double rd  = EPSQ * z[k] + p[k] + (yav[i] + ydv[lane] + yt * fe[k]) + (l2[k] - l1[k]);
      double tt1 = (mu01 - l1[k] * z[k]) * is1;
      double tt2 = (l2[k] * (z[k] - 1.0) + mu01) * is2;
      double r = -(rd - tt1 + tt2);
      rz[k] = r;
      double g = r * D;
      double sD  = wsum(D);
      double sED = wsum(ev * D);
      double sg  = wsum(g);
      if (lane == 0) {
        Rhv[i]  = sD + SREG;
        Ruv[i]  = sED;
        rhs1[i] = sg + req1[i];
      }
      cD  += D;  cfD += fr[k] * D;  cg += g;
      qac += fe[k] * fe[k] * D;
      fgac += fe[k] * g;
    }
    cpA[w][lane] = cD; cpB[w][lane] = cfD; cpC[w][lane] = cg;
    {
      double a = wsum(qac), c = wsum(fgac);
      if (lane == 0) { wpA[w] = a; wpB[w] = c; }
    }
    __syncthreads();

    // ---- Phase D: finalize col sums, border vectors, write DnT -----------
    if (tid < 64) {
      double a = 0.0, c = 0.0, d = 0.0;
      for (int q = 0; q < 8; ++q) { a += cpA[q][tid]; c += cpB[q][tid]; d += cpC[q][tid]; }
      ccv[tid]   = a;                 // colsum(invD)
      wvv[tid]   = evec[tid] * c;     // w_j
      rhs2v[tid] = d + req2[tid];
      double ir  = 1.0 / sqrt(Rhv[tid]);
      double u   = fvec[tid] * Ruv[tid];
      uvv[tid] = u;
      usv[tid] = u * ir;
      rsv[tid] = rhs1[tid] * ir;
    }
    if (tid == 0) {
      double a = 0.0, c = 0.0;
      for (int q = 0; q < 8; ++q) { a += wpA[q]; c += wpB[q]; }
      scal[2] = a;             // q
      scal[3] = c + scal[1];   // rhs3
    }
#pragma unroll
    for (int k = 0; k < NCH; ++k) {
      int i = w + 8 * k;
      DnT[lane][i] = dinv[k] / sqrt(Rhv[i]);
    }
    __syncthreads();

    // ---- Phase E: build augmented reduced Schur Mg = [M | rhs_d | mw] ----
    {
      int j = tid >> 3, c0 = tid & 7;
#pragma unroll 1
      for (int m = 0; m < 9; ++m) {
        int l = c0 + 8 * m;
        if (l < 64) {
          double acc = 0.0;
#pragma unroll 8
          for (int i = 0; i < 64; ++i) acc += DnT[j][i] * DnT[l][i];
          Mg[j][l] = ((j == l) ? (ccv[j] + SREG) : 0.0) - acc;
        } else if (l == 64) {
          double acc = 0.0;
#pragma unroll 8
          for (int i = 0; i < 64; ++i) acc += DnT[j][i] * rsv[i];
          Mg[j][64] = rhs2v[j] - acc;
        } else if (l == 65) {
          double acc = 0.0;
#pragma unroll 8
          for (int i = 0; i < 64; ++i) acc += DnT[j][i] * usv[i];
          double vv = wvv[j] - acc;
          Mg[j][65] = vv;
          mw0[j] = vv;
        }
      }
    }
    __syncthreads();

    // ---- Phase F: block Gauss-Jordan, 4 panels of 16 ---------------------
    // After all 4 panels, Mg[j][64] = h1_j, Mg[j][65] = h2_j (full solution).
#pragma unroll
    for (int pk = 0; pk < 4; ++pk) {
      const int k0   = 16 * pk;
      const int rest = 66 - k0 - 16;   // 50, 34, 18, 2

      // -- F1: invert 16x16 pivot block in one wave (registers + shfl) ----
      if (w == 0) {
        const int r = lane >> 2, q = lane & 3;
        double Brow[4];
#pragma unroll
        for (int e = 0; e < 4; ++e) Brow[e] = Mg[k0 + r][k0 + ((e << 2) | q)];
#pragma unroll
        for (int t = 0; t < 16; ++t) {
          const int et = t >> 2, qt = t & 3;
          double pm = __shfl(Brow[et], (r << 2) | qt, 64);   // my row's col-t entry
          double pv = __shfl(Brow[et], (t << 2) | qt, 64);   // pivot value
          double pr0 = __shfl(Brow[0], (t << 2) | q, 64);    // pivot row, my cols
          double pr1 = __shfl(Brow[1], (t << 2) | q, 64);
          double pr2 = __shfl(Brow[2], (t << 2) | q, 64);
          double pr3 = __shfl(Brow[3], (t << 2) | q, 64);
          double ip = 1.0 / pv;
          double ps0 = pr0 * ip, ps1 = pr1 * ip, ps2 = pr2 * ip, ps3 = pr3 * ip;
          if (r == t) {
            Brow[0] = ps0; Brow[1] = ps1; Brow[2] = ps2; Brow[3] = ps3;
            if (q == qt) Brow[et] = ip;
          } else {
            Brow[0] -= pm * ps0; Brow[1] -= pm * ps1;
            Brow[2] -= pm * ps2; Brow[3] -= pm * ps3;
            if (q == qt) Brow[et] = -pm * ip;
          }
        }
#pragma unroll
        for (int e = 0; e < 4; ++e) Binv[r][(e << 2) | q] = Brow[e];
      }
      __syncthreads();

      // -- F2: Pbuf = Binv * Mg[panel rows, rest cols] --------------------
      for (int o = tid; o < 16 * rest; o += NT) {
        int t = o / rest, c = o - t * rest;
        double acc = 0.0;
#pragma unroll
        for (int s = 0; s < 16; ++s) acc += Binv[t][s] * Mg[k0 + s][k0 + 16 + c];
        Pbuf[t][c] = acc;
      }
      __syncthreads();

      // -- F3: eliminate panel columns from all other rows; set panel rows -
      for (int o = tid; o < 48 * rest; o += NT) {
        int rr = o / rest, c = o - rr * rest;
        int r = rr < k0 ? rr : rr + 16;
        double acc = Mg[r][k0 + 16 + c];
#pragma unroll
        for (int t = 0; t < 16; ++t) acc -= Mg[r][k0 + t] * Pbuf[t][c];
        Mg[r][k0 + 16 + c] = acc;
      }
      for (int o = tid; o < 16 * rest; o += NT) {
        int t = o / rest, c = o - t * rest;
        Mg[k0 + t][k0 + 16 + c] = Pbuf[t][c];
      }
      __syncthreads();
    }

    // ---- Phase H: fairness border solve (wave 0 only) --------------------
    if (w == 0) {
      double h1 = Mg[lane][64], h2 = Mg[lane][65];
      double a1 = wsum(usv[lane] * usv[lane]);
      double a2 = wsum(usv[lane] * rsv[lane]);
      double a3 = wsum(mw0[lane] * h1);
      double a4 = wsum(mw0[lane] * h2);
      double qp  = scal[2] + SREG - a1;
      double r3p = scal[3] - a2;
      double tloc = (r3p - a3) / (qp - a4);
      ddv[lane] = h1 - tloc * h2;
      if (lane == 0) scal[4] = tloc;
    }
    __syncthreads();

    // ---- da (row duals) ---------------------------------------------------
    const double tf = scal[4];
#pragma unroll
    for (int k = 0; k < NCH; ++k) {
      int i = w + 8 * k;
      double rdot = wsum(dinv[k] * ddv[lane]);
      if (lane == 0) dav[i] = (rhs1[i] - rdot - uvv[i] * tf) / Rhv[i];
    }
    __syncthreads();

    // ---- Phase I: dz/ds/dlam, alpha, update ------------------------------
    double amin = BIGV;
    double dz[NCH];
#pragma unroll
    for (int k = 0; k < NCH; ++k) {
      int i = w + 8 * k;
      double dyA = dav[i] + ddv[lane] + tf * fe[k];
      double d   = (rz[k] - dyA) * dinv[k];
      dz[k] = d;
      double ri1 = s1[k] - z[k];
      double ri2 = z[k] + s2[k] - 1.0;
      double ds1 = d - ri1;
      double ds2 = -ri2 - d;
      double rc1 = l1[k] * s1[k] - mu01;
      double rc2 = l2[k] * s2[k] - mu01;
      double dl1 = (-rc1 - l1[k] * ds1) / s1[k];
      double dl2 = (-rc2 - l2[k] * ds2) / s2[k];
      if (ds1 < 0.0) amin = fmin(amin, -s1[k] / ds1);
      if (ds2 < 0.0) amin = fmin(amin, -s2[k] / ds2);
      if (dl1 < 0.0) amin = fmin(amin, -l1[k] / dl1);
      if (dl2 < 0.0) amin = fmin(amin, -l2[k] / dl2);
    }
    amin = wmin(amin);
    if (lane == 0) wpA[w] = amin;
    __syncthreads();
    if (tid == 0) {
      double a = wpA[0];
      for (int q = 1; q < 8; ++q) a = fmin(a, wpA[q]);
      scal[5] = fmin(1.0, 0.99 * a);
    }
    __syncthreads();
    const double al = scal[5];
#pragma unroll
    for (int k = 0; k < NCH; ++k) {
      double d   = dz[k];
      double ri1 = s1[k] - z[k];
      double ri2 = z[k] + s2[k] - 1.0;
      double ds1 = d - ri1;
      double ds2 = -ri2 - d;
      double rc1 = l1[k] * s1[k] - mu01;
      double rc2 = l2[k] * s2[k] - mu01;
      double dl1 = (-rc1 - l1[k] * ds1) / s1[k];
      double dl2 = (-rc2 - l2[k] * ds2) / s2[k];
      z[k]  += al * d;
      s1[k] += al * ds1;
      s2[k] += al * ds2;
      l1[k] += al * dl1;
      l2[k] += al * dl2;
    }
    if (tid < 64) {
      yav[tid] += al * dav[tid];
      ydv[tid] += al * ddv[tid];
    }
    if (tid == 0) scal[6] += al * scal[4];
    __syncthreads();
  }

  // ---- output (fp32) ------------------------------------------------------
#pragma unroll
  for (int k = 0; k < NCH; ++k) {
    int e = tid + NT * k;
    outp[(size_t)b * NXX + e] = (float)z[k];
  }
}

extern "C" void kernel_launch(void* const* d_in, const int* in_sizes, int n_in,
                              void* d_out, int out_size, void* d_ws, size_t ws_size,
                              hipStream_t stream)
{
  const float* x   = (const float*)d_in[0];
  const float* gid = (const float*)d_in[1];
  const float* ex  = (const float*)d_in[2];
  float* out = (float*)d_out;
  int nb = in_sizes[0] / NXX;   // 32 batches
  hipLaunchKernelGGL(ipm_kernel, dim3(nb), dim3(NT), 0, stream, x, gid, ex, out);
}

// Round 4
// 1470.544 us; speedup vs baseline: 1.4849x; 1.0713x over previous
//
#include <hip/hip_runtime.h>
#include <math.h>

#define NN    64
#define NXX   4096
#define NT    512
#define NCH   8          // elements per thread = NXX/NT
#define NITER 25
#define EPSQ  0.1
#define SREG  1e-9
#define BIGV  1e10

// ---- wave (64-lane) reductions -------------------------------------------
__device__ __forceinline__ double wsum(double v) {
#pragma unroll
  for (int m = 32; m > 0; m >>= 1) v += __shfl_xor(v, m, 64);
  return v;
}
__device__ __forceinline__ double wmin(double v) {
#pragma unroll
  for (int m = 32; m > 0; m >>= 1) v = fmin(v, __shfl_xor(v, m, 64));
  return v;
}
__device__ __forceinline__ double wmax(double v) {
#pragma unroll
  for (int m = 32; m > 0; m >>= 1) v = fmax(v, __shfl_xor(v, m, 64));
  return v;
}

// One block per batch element. 512 threads = 8 waves.
// Element e = tid + 512*k  (k=0..7). grid row i = e>>6 = w + 8k, col j = lane.
__global__ __launch_bounds__(NT, 2)
void ipm_kernel(const float* __restrict__ xin, const float* __restrict__ gidin,
                const float* __restrict__ expin, float* __restrict__ outp)
{
  const int b    = blockIdx.x;
  const int tid  = threadIdx.x;
  const int lane = tid & 63;
  const int w    = tid >> 6;     // wave id 0..7

  // ---- LDS ----------------------------------------------------------------
  __shared__ double DnT[64][65];     // DnT[j][i] = invD(i,j)/sqrt(Rh_i)
  __shared__ double Mg[64][67];      // augmented reduced Schur [M | rhs_d | mw]
  __shared__ double Pbuf[16][52];    // B^{-1} * panel-rest rows
  __shared__ double Binv[16][18];    // 16x16 pivot-block inverse
  __shared__ double cpZ[8][64], cpA[8][64], cpB[8][64], cpC[8][64];
  __shared__ double rhs1[64], rhs2v[64];
  __shared__ double Rhv[64], Ruv[64], ccv[64], wvv[64];
  __shared__ double usv[64], rsv[64], uvv[64], mw0[64];
  __shared__ double ddv[64];
  __shared__ double yav[64], ydv[64];
  __shared__ double fvec[64], evec[64];
  __shared__ double wpFz[8], wpMu[8], wpQ[8], wpFg[8], wpS[8], wpL[8];
  __shared__ double scal[8];  // 4=dt 5=alpha 6=yt 7=gsum

  // ---- constants f, e; init y --------------------------------------------
  if (tid < 64) {
    fvec[tid] = (double)gidin[tid];   // reference uses group_ids[0] for ALL batches
    evec[tid] = (double)expin[tid];
    yav[tid] = 0.0; ydv[tid] = 0.0;
  }
  if (tid == 0) scal[6] = 0.0;
  __syncthreads();
  if (tid == 0) {
    double gs = 0.0;
    for (int i = 0; i < 64; ++i) gs += fvec[i];
    scal[7] = gs;
  }
  __syncthreads();
  if (tid < 64) {
    double g = fvec[tid], gs = scal[7];
    fvec[tid] = g / gs - (1.0 - g) / (64.0 - gs);
  }
  __syncthreads();

  // ---- per-thread state ---------------------------------------------------
  double p[NCH], z[NCH], s1[NCH], s2[NCH], l1[NCH], l2[NCH], fe[NCH];
  const double ev = evec[lane];
#pragma unroll
  for (int k = 0; k < NCH; ++k) {
    int e = tid + NT * k;
    p[k]  = (double)xin[(size_t)b * NXX + e];
    z[k] = 0.0; s1[k] = 1.0; s2[k] = 1.0; l1[k] = 1.0; l2[k] = 1.0;
    fe[k] = fvec[w + 8 * k] * ev;
  }

  // ======================= main IPM loop ==================================
  for (int iter = 0; iter < NITER; ++iter) {
    // ---- Phase A: row sums of z, fairness/mu partials --------------------
    double rq1[NCH];
    double cz = 0.0, fz = 0.0, msl = 0.0;
#pragma unroll
    for (int k = 0; k < NCH; ++k) {
      rq1[k] = wsum(z[k]) - 1.0;
      cz  += z[k];
      fz  += fe[k] * z[k];
      msl += s1[k] * l1[k] + s2[k] * l2[k];
    }
    cpZ[w][lane] = cz;
    {
      double a = wsum(fz), c = wsum(msl);
      if (lane == 0) { wpFz[w] = a; wpMu[w] = c; }
    }
    __syncthreads();

    // ---- Phase C: invD, rhs_z, first-order reductions, DnT write ---------
    double mu8 = 0.0;
#pragma unroll
    for (int q = 0; q < 8; ++q) mu8 += wpMu[q];
    const double mu01 = 0.1 * (mu8 / 8192.0);
    const double yt   = scal[6];
    double dinv[NCH], rz[NCH], is1[NCH], is2[NCH];
    double cD = 0.0, cfD = 0.0, cg = 0.0, qac = 0.0, fgac = 0.0;
#pragma unroll
    for (int k = 0; k < NCH; ++k) {
      int i = w + 8 * k;
      is1[k] = 1.0 / s1[k];  is2[k] = 1.0 / s2[k];
      double D = 1.0 / (EPSQ + l1[k] * is1[k] + l2[k] * is2[k]);
      dinv[k] = D;
      double rd  = EPSQ * z[k] + p[k] + (yav[i] + ydv[lane] + yt * fe[k]) + (l2[k] - l1[k]);
      double tt1 = (mu01 - l1[k] * z[k]) * is1[k];
      double tt2 = (l2[k] * (z[k] - 1.0) + mu01) * is2[k];
      double r = -(rd - tt1 + tt2);
      rz[k] = r;
      double g = r * D;
      double sD  = wsum(D);
      double sED = wsum(ev * D);
      double sg  = wsum(g);
      double Rh  = sD + SREG;
      if (lane == 0) {
        Rhv[i]  = Rh;
        Ruv[i]  = sED;
        rhs1[i] = sg + rq1[k];
      }
      DnT[lane][i] = D * rsqrt(Rh);
      cD  += D;  cfD += fvec[i] * D;  cg += g;
      qac += fe[k] * fe[k] * D;
      fgac += fe[k] * g;
    }
    cpA[w][lane] = cD; cpB[w][lane] = cfD; cpC[w][lane] = cg;
    {
      double a = wsum(qac), c = wsum(fgac);
      if (lane == 0) { wpQ[w] = a; wpFg[w] = c; }
    }
    __syncthreads();

    // ---- Phase D: column-sum finalize + border vectors (wave 0) ----------
    if (tid < 64) {
      double sZ = 0.0, sA = 0.0, sB = 0.0, sC = 0.0;
#pragma unroll
      for (int q = 0; q < 8; ++q) {
        sZ += cpZ[q][tid]; sA += cpA[q][tid]; sB += cpB[q][tid]; sC += cpC[q][tid];
      }
      ccv[tid]   = sA;
      wvv[tid]   = evec[tid] * sB;
      rhs2v[tid] = sC + sZ - 1.0;
      double ir  = rsqrt(Rhv[tid]);
      double u   = fvec[tid] * Ruv[tid];
      uvv[tid] = u;
      usv[tid] = u * ir;
      rsv[tid] = rhs1[tid] * ir;
    }
    __syncthreads();

    // ---- Phase E: Mg = diag(ccv)+SREG - DnT DnT^T, 4x2 register blocks ---
    // Thread -> rows r0..r0+3 (half-wave broadcast loads), cols c0..c0+1.
    {
      const int r0 = (tid >> 5) << 2;    // 0,4,...,60
      const int c0 = (tid & 31) << 1;    // 0,2,...,62
      double m00=0.0,m01=0.0,m10=0.0,m11=0.0,m20=0.0,m21=0.0,m30=0.0,m31=0.0;
#pragma unroll 4
      for (int i = 0; i < 64; ++i) {
        double a0 = DnT[r0+0][i], a1 = DnT[r0+1][i];
        double a2 = DnT[r0+2][i], a3 = DnT[r0+3][i];
        double b0v = DnT[c0+0][i], b1v = DnT[c0+1][i];
        m00 += a0*b0v; m01 += a0*b1v;
        m10 += a1*b0v; m11 += a1*b1v;
        m20 += a2*b0v; m21 += a2*b1v;
        m30 += a3*b0v; m31 += a3*b1v;
      }
      Mg[r0+0][c0+0] = ((r0+0)==(c0+0) ? ccv[r0+0]+SREG : 0.0) - m00;
      Mg[r0+0][c0+1] = ((r0+0)==(c0+1) ? ccv[r0+0]+SREG : 0.0) - m01;
      Mg[r0+1][c0+0] = ((r0+1)==(c0+0) ? ccv[r0+1]+SREG : 0.0) - m10;
      Mg[r0+1][c0+1] = ((r0+1)==(c0+1) ? ccv[r0+1]+SREG : 0.0) - m11;
      Mg[r0+2][c0+0] = ((r0+2)==(c0+0) ? ccv[r0+2]+SREG : 0.0) - m20;
      Mg[r0+2][c0+1] = ((r0+2)==(c0+1) ? ccv[r0+2]+SREG : 0.0) - m21;
      Mg[r0+3][c0+0] = ((r0+3)==(c0+0) ? ccv[r0+3]+SREG : 0.0) - m30;
      Mg[r0+3][c0+1] = ((r0+3)==(c0+1) ? ccv[r0+3]+SREG : 0.0) - m31;

      // border columns 64 (rhs_d) / 65 (mw): 128 dots of length 64
      int d = 16 * w + (lane >> 2);
      int j = d & 63;
      int cc = d >> 6;                 // waves 0-3 -> col 64, waves 4-7 -> col 65
      int iq = (lane & 3) * 16;
      double acc = 0.0;
#pragma unroll
      for (int i = 0; i < 16; ++i) {
        double vv = cc ? usv[iq + i] : rsv[iq + i];
        acc += DnT[j][iq + i] * vv;
      }
      acc += __shfl_xor(acc, 1, 64);
      acc += __shfl_xor(acc, 2, 64);
      if ((lane & 3) == 0) {
        if (cc == 0) Mg[j][64] = rhs2v[j] - acc;
        else { double vv2 = wvv[j] - acc; Mg[j][65] = vv2; mw0[j] = vv2; }
      }
    }
    __syncthreads();

    // ---- Phase F: block Gauss-Jordan, 4 panels of 16 ---------------------
#pragma unroll
    for (int pk = 0; pk < 4; ++pk) {
      const int k0   = 16 * pk;
      const int rest = 66 - k0 - 16;   // 50, 34, 18, 2

      // -- F1: invert 16x16 pivot block in one wave (registers + shfl) ----
      if (w == 0) {
        const int r = lane >> 2, q = lane & 3;
        double Brow[4];
#pragma unroll
        for (int e = 0; e < 4; ++e) Brow[e] = Mg[k0 + r][k0 + ((e << 2) | q)];
#pragma unroll
        for (int t = 0; t < 16; ++t) {
          const int et = t >> 2, qt = t & 3;
          double pm = __shfl(Brow[et], (r << 2) | qt, 64);
          double pv = __shfl(Brow[et], (t << 2) | qt, 64);
          double pr0 = __shfl(Brow[0], (t << 2) | q, 64);
          double pr1 = __shfl(Brow[1], (t << 2) | q, 64);
          double pr2 = __shfl(Brow[2], (t << 2) | q, 64);
          double pr3 = __shfl(Brow[3], (t << 2) | q, 64);
          double ip = 1.0 / pv;
          double ps0 = pr0 * ip, ps1 = pr1 * ip, ps2 = pr2 * ip, ps3 = pr3 * ip;
          if (r == t) {
            Brow[0] = ps0; Brow[1] = ps1; Brow[2] = ps2; Brow[3] = ps3;
            if (q == qt) Brow[et] = ip;
          } else {
            Brow[0] -= pm * ps0; Brow[1] -= pm * ps1;
            Brow[2] -= pm * ps2; Brow[3] -= pm * ps3;
            if (q == qt) Brow[et] = -pm * ip;
          }
        }
#pragma unroll
        for (int e = 0; e < 4; ++e) Binv[r][(e << 2) | q] = Brow[e];
      }
      __syncthreads();

      // -- F2: Pbuf = Binv * Mg[panel rows, rest cols] --------------------
      for (int o = tid; o < 16 * rest; o += NT) {
        int t = o / rest, c = o - t * rest;
        double acc = 0.0;
#pragma unroll
        for (int s = 0; s < 16; ++s) acc += Binv[t][s] * Mg[k0 + s][k0 + 16 + c];
        Pbuf[t][c] = acc;
      }
      __syncthreads();

      // -- F3: eliminate panel columns from all other rows; set panel rows -
      for (int o = tid; o < 48 * rest; o += NT) {
        int rr = o / rest, c = o - rr * rest;
        int r = rr < k0 ? rr : rr + 16;
        double acc = Mg[r][k0 + 16 + c];
#pragma unroll
        for (int t = 0; t < 16; ++t) acc -= Mg[r][k0 + t] * Pbuf[t][c];
        Mg[r][k0 + 16 + c] = acc;
      }
      for (int o = tid; o < 16 * rest; o += NT) {
        int t = o / rest, c = o - t * rest;
        Mg[k0 + t][k0 + 16 + c] = Pbuf[t][c];
      }
      __syncthreads();
    }

    // ---- Phase H: fairness border solve (wave 0 only) --------------------
    if (w == 0) {
      double qsum = 0.0, fg = 0.0, fzs = 0.0;
#pragma unroll
      for (int q = 0; q < 8; ++q) { qsum += wpQ[q]; fg += wpFg[q]; fzs += wpFz[q]; }
      double h1 = Mg[lane][64], h2 = Mg[lane][65];
      double a1 = wsum(usv[lane] * usv[lane]);
      double a2 = wsum(usv[lane] * rsv[lane]);
      double a3 = wsum(mw0[lane] * h1);
      double a4 = wsum(mw0[lane] * h2);
      double qp  = qsum + SREG - a1;
      double r3p = (fg + fzs) - a2;
      double tloc = (r3p - a3) / (qp - a4);
      ddv[lane] = h1 - tloc * h2;
      if (lane == 0) scal[4] = tloc;
    }
    __syncthreads();

    // ---- Phase I: row duals (in-register), dz/ds/dlam, alpha -------------
    const double tf = scal[4];
    double dar[NCH];
    double bs = 0.0;          // s-side rate max
    double rl = BIGV;         // lambda-side ratio min
#pragma unroll
    for (int k = 0; k < NCH; ++k) {
      int i = w + 8 * k;
      double rdot = wsum(dinv[k] * ddv[lane]);
      double dv = (rhs1[i] - rdot - uvv[i] * tf) / Rhv[i];
      dar[k] = dv;
      double d   = (rz[k] - (dv + ddv[lane] + tf * fe[k])) * dinv[k];
      double ds1 = d - (s1[k] - z[k]);
      double ds2 = -(z[k] + s2[k] - 1.0) - d;
      bs = fmax(bs, fmax(-ds1 * is1[k], -ds2 * is2[k]));
      double dl1 = (-(l1[k] * s1[k] - mu01) - l1[k] * ds1) * is1[k];
      double dl2 = (-(l2[k] * s2[k] - mu01) - l2[k] * ds2) * is2[k];
      if (dl1 < 0.0) rl = fmin(rl, -l1[k] / dl1);
      if (dl2 < 0.0) rl = fmin(rl, -l2[k] / dl2);
    }
    bs = wmax(bs);
    rl = wmin(rl);
    if (lane == 0) { wpS[w] = bs; wpL[w] = rl; }
    __syncthreads();
    if (tid == 0) {
      double bm = wpS[0], rm = wpL[0];
      for (int q = 1; q < 8; ++q) { bm = fmax(bm, wpS[q]); rm = fmin(rm, wpL[q]); }
      double a_s = bm > 0.0 ? 1.0 / bm : BIGV;
      scal[5] = fmin(1.0, 0.99 * fmin(a_s, rm));
    }
    __syncthreads();

    // ---- update ----------------------------------------------------------
    const double al = scal[5];
#pragma unroll
    for (int k = 0; k < NCH; ++k) {
      double d   = (rz[k] - (dar[k] + ddv[lane] + tf * fe[k])) * dinv[k];
      double ds1 = d - (s1[k] - z[k]);
      double ds2 = -(z[k] + s2[k] - 1.0) - d;
      double dl1 = (-(l1[k] * s1[k] - mu01) - l1[k] * ds1) * is1[k];
      double dl2 = (-(l2[k] * s2[k] - mu01) - l2[k] * ds2) * is2[k];
      z[k]  += al * d;
      s1[k] += al * ds1;
      s2[k] += al * ds2;
      l1[k] += al * dl1;
      l2[k] += al * dl2;
      if (lane == 0) yav[w + 8 * k] += al * dar[k];
    }
    if (tid < 64) ydv[tid] += al * ddv[tid];
    if (tid == 0) scal[6] += al * tf;
    // no end barrier: Phase A's barrier orders these LDS writes before C's reads
  }

  // ---- output (fp32) ------------------------------------------------------
#pragma unroll
  for (int k = 0; k < NCH; ++k) {
    int e = tid + NT * k;
    outp[(size_t)b * NXX + e] = (float)z[k];
  }
}

extern "C" void kernel_launch(void* const* d_in, const int* in_sizes, int n_in,
                              void* d_out, int out_size, void* d_ws, size_t ws_size,
                              hipStream_t stream)
{
  const float* x   = (const float*)d_in[0];
  const float* gid = (const float*)d_in[1];
  const float* ex  = (const float*)d_in[2];
  float* out = (float*)d_out;
  int nb = in_sizes[0] / NXX;   // 32 batches
  hipLaunchKernelGGL(ipm_kernel, dim3(nb), dim3(NT), 0, stream, x, gid, ex, out);
}

// Round 5
// 1294.676 us; speedup vs baseline: 1.6866x; 1.1358x over previous
//
#include <hip/hip_runtime.h>
#include <math.h>

#define NN    64
#define NXX   4096
#define NT    512
#define NCH   8          // elements per thread = NXX/NT
#define NITER 25
#define EPSQ  0.1
#define SREG  1e-9
#define BIGV  1e10

// ---- wave (64-lane) reductions -------------------------------------------
__device__ __forceinline__ double wsum(double v) {
#pragma unroll
  for (int m = 32; m > 0; m >>= 1) v += __shfl_xor(v, m, 64);
  return v;
}
__device__ __forceinline__ double wmin(double v) {
#pragma unroll
  for (int m = 32; m > 0; m >>= 1) v = fmin(v, __shfl_xor(v, m, 64));
  return v;
}
__device__ __forceinline__ double wmax(double v) {
#pragma unroll
  for (int m = 32; m > 0; m >>= 1) v = fmax(v, __shfl_xor(v, m, 64));
  return v;
}

// 16x16 pivot-block inversion in one wave (registers + shfl), rcp+2NR divide.
// Reads Mg[K0..K0+15][K0..K0+15], writes Binv. Valid pivots: SPD trailing blocks.
#define F1_INVERT(K0)                                                         \
  {                                                                           \
    const int r_ = lane >> 2, q_ = lane & 3;                                  \
    double Brow[4];                                                           \
    _Pragma("unroll")                                                         \
    for (int e = 0; e < 4; ++e) Brow[e] = Mg[(K0) + r_][(K0) + ((e << 2) | q_)]; \
    _Pragma("unroll")                                                         \
    for (int t = 0; t < 16; ++t) {                                            \
      const int et = t >> 2, qt = t & 3;                                      \
      double pm  = __shfl(Brow[et], (r_ << 2) | qt, 64);                      \
      double pv  = __shfl(Brow[et], (t << 2) | qt, 64);                       \
      double pr0 = __shfl(Brow[0], (t << 2) | q_, 64);                        \
      double pr1 = __shfl(Brow[1], (t << 2) | q_, 64);                        \
      double pr2 = __shfl(Brow[2], (t << 2) | q_, 64);                        \
      double pr3 = __shfl(Brow[3], (t << 2) | q_, 64);                        \
      double ip = __builtin_amdgcn_rcp(pv);                                   \
      ip = ip * (2.0 - pv * ip);                                              \
      ip = ip * (2.0 - pv * ip);                                              \
      double ps0 = pr0 * ip, ps1 = pr1 * ip, ps2 = pr2 * ip, ps3 = pr3 * ip;  \
      if (r_ == t) {                                                          \
        Brow[0] = ps0; Brow[1] = ps1; Brow[2] = ps2; Brow[3] = ps3;           \
        if (q_ == qt) Brow[et] = ip;                                          \
      } else {                                                                \
        Brow[0] -= pm * ps0; Brow[1] -= pm * ps1;                             \
        Brow[2] -= pm * ps2; Brow[3] -= pm * ps3;                             \
        if (q_ == qt) Brow[et] = -pm * ip;                                    \
      }                                                                       \
    }                                                                         \
    _Pragma("unroll")                                                         \
    for (int e = 0; e < 4; ++e) Binv[r_][(e << 2) | q_] = Brow[e];            \
  }

// pair index -> (j,l), j>l, idx = j(j-1)/2 + l
__device__ __forceinline__ void pair_jl(int idx, int& j, int& l) {
  j = (int)((1.0 + sqrt(8.0 * (double)idx + 1.0)) * 0.5);
  while (j * (j - 1) / 2 > idx) --j;
  while ((j + 1) * j / 2 <= idx) ++j;
  l = idx - j * (j - 1) / 2;
}

// One block per batch element. 512 threads = 8 waves.
// Element e = tid + 512*k  (k=0..7). grid row i = e>>6 = w + 8k, col j = lane.
__global__ __launch_bounds__(NT, 2)
void ipm_kernel(const float* __restrict__ xin, const float* __restrict__ gidin,
                const float* __restrict__ expin, float* __restrict__ outp)
{
  const int b    = blockIdx.x;
  const int tid  = threadIdx.x;
  const int lane = tid & 63;
  const int w    = tid >> 6;     // wave id 0..7

  // ---- LDS ----------------------------------------------------------------
  __shared__ double DnT[64][65];     // DnT[j][i] = invD(i,j)/sqrt(Rh_i)
  __shared__ double Mg[64][67];      // augmented reduced Schur [M | rhs_d | mw]
  __shared__ double Pbuf[16][52];    // B^{-1} * panel-rest rows
  __shared__ double Binv[16][18];    // 16x16 pivot-block inverse
  __shared__ double cpZ[8][64], cpA[8][64], cpB[8][64], cpC[8][64];
  __shared__ double rhs1[64], rhs2v[64];
  __shared__ double Rhv[64], Ruv[64], ccv[64], wvv[64];
  __shared__ double usv[64], rsv[64], uvv[64], mw0[64];
  __shared__ double yav[64], ydv[64];
  __shared__ double fvec[64], evec[64];
  __shared__ double wpFz[8], wpMu[8], wpQ[8], wpFg[8], wpS[8], wpL[8];
  __shared__ double scal[8];  // 6=yt 7=gsum

  // ---- constants f, e; init y --------------------------------------------
  if (tid < 64) {
    fvec[tid] = (double)gidin[tid];   // reference uses group_ids[0] for ALL batches
    evec[tid] = (double)expin[tid];
    yav[tid] = 0.0; ydv[tid] = 0.0;
  }
  if (tid == 0) scal[6] = 0.0;
  __syncthreads();
  if (tid == 0) {
    double gs = 0.0;
    for (int i = 0; i < 64; ++i) gs += fvec[i];
    scal[7] = gs;
  }
  __syncthreads();
  if (tid < 64) {
    double g = fvec[tid], gs = scal[7];
    fvec[tid] = g / gs - (1.0 - g) / (64.0 - gs);
  }
  __syncthreads();

  // ---- per-thread state ---------------------------------------------------
  double p[NCH], z[NCH], s1[NCH], s2[NCH], l1[NCH], l2[NCH], fe[NCH];
  const double ev = evec[lane];
#pragma unroll
  for (int k = 0; k < NCH; ++k) {
    int e = tid + NT * k;
    p[k]  = (double)xin[(size_t)b * NXX + e];
    z[k] = 0.0; s1[k] = 1.0; s2[k] = 1.0; l1[k] = 1.0; l2[k] = 1.0;
    fe[k] = fvec[w + 8 * k] * ev;
  }

  // ======================= main IPM loop ==================================
  for (int iter = 0; iter < NITER; ++iter) {
    // ---- Phase A: row sums of z, fairness/mu partials --------------------
    double rq1[NCH];
    double cz = 0.0, fz = 0.0, msl = 0.0;
#pragma unroll
    for (int k = 0; k < NCH; ++k) {
      rq1[k] = wsum(z[k]) - 1.0;
      cz  += z[k];
      fz  += fe[k] * z[k];
      msl += s1[k] * l1[k] + s2[k] * l2[k];
    }
    cpZ[w][lane] = cz;
    {
      double a = wsum(fz), c = wsum(msl);
      if (lane == 0) { wpFz[w] = a; wpMu[w] = c; }
    }
    __syncthreads();

    // ---- Phase C: invD, rhs_z, first-order reductions, DnT write ---------
    double mu8 = 0.0;
#pragma unroll
    for (int q = 0; q < 8; ++q) mu8 += wpMu[q];
    const double mu01 = 0.1 * (mu8 / 8192.0);
    const double yt   = scal[6];
    double dinv[NCH], rz[NCH], is1[NCH], is2[NCH];
    double cD = 0.0, cfD = 0.0, cg = 0.0, qac = 0.0, fgac = 0.0;
#pragma unroll
    for (int k = 0; k < NCH; ++k) {
      int i = w + 8 * k;
      is1[k] = 1.0 / s1[k];  is2[k] = 1.0 / s2[k];
      double D = 1.0 / (EPSQ + l1[k] * is1[k] + l2[k] * is2[k]);
      dinv[k] = D;
      double rd  = EPSQ * z[k] + p[k] + (yav[i] + ydv[lane] + yt * fe[k]) + (l2[k] - l1[k]);
      double tt1 = (mu01 - l1[k] * z[k]) * is1[k];
      double tt2 = (l2[k] * (z[k] - 1.0) + mu01) * is2[k];
      double r = -(rd - tt1 + tt2);
      rz[k] = r;
      double g = r * D;
      double sD  = wsum(D);
      double sED = wsum(ev * D);
      double sg  = wsum(g);
      double Rh  = sD + SREG;
      if (lane == 0) {
        Rhv[i]  = Rh;
        Ruv[i]  = sED;
        rhs1[i] = sg + rq1[k];
      }
      DnT[lane][i] = D * rsqrt(Rh);
      cD  += D;  cfD += fvec[i] * D;  cg += g;
      qac += fe[k] * fe[k] * D;
      fgac += fe[k] * g;
    }
    cpA[w][lane] = cD; cpB[w][lane] = cfD; cpC[w][lane] = cg;
    {
      double a = wsum(qac), c = wsum(fgac);
      if (lane == 0) { wpQ[w] = a; wpFg[w] = c; }
    }
    __syncthreads();

    // ---- Phase D: column-sum finalize + border vectors (wave 0) ----------
    if (tid < 64) {
      double sZ = 0.0, sA = 0.0, sB = 0.0, sC = 0.0;
#pragma unroll
      for (int q = 0; q < 8; ++q) {
        sZ += cpZ[q][tid]; sA += cpA[q][tid]; sB += cpB[q][tid]; sC += cpC[q][tid];
      }
      ccv[tid]   = sA;
      wvv[tid]   = evec[tid] * sB;
      rhs2v[tid] = sC + sZ - 1.0;
      double ir  = rsqrt(Rhv[tid]);
      double u   = fvec[tid] * Ruv[tid];
      uvv[tid] = u;
      usv[tid] = u * ir;
      rsv[tid] = rhs1[tid] * ir;
    }
    __syncthreads();

    // ---- Phase E-main: upper-triangle 4x2 tiles (272 thr) + borders ------
    if (tid < 272) {
      int R = 0;
#pragma unroll
      for (int r = 1; r < 16; ++r) if (tid >= r * (33 - r)) R = r;
      const int C  = 2 * R + (tid - R * (33 - R));
      const int r0 = R << 2, c0 = C << 1;
      double m00=0.0,m01=0.0,m10=0.0,m11=0.0,m20=0.0,m21=0.0,m30=0.0,m31=0.0;
#pragma unroll 4
      for (int i = 0; i < 64; ++i) {
        double a0 = DnT[r0+0][i], a1 = DnT[r0+1][i];
        double a2 = DnT[r0+2][i], a3 = DnT[r0+3][i];
        double b0v = DnT[c0+0][i], b1v = DnT[c0+1][i];
        m00 += a0*b0v; m01 += a0*b1v;
        m10 += a1*b0v; m11 += a1*b1v;
        m20 += a2*b0v; m21 += a2*b1v;
        m30 += a3*b0v; m31 += a3*b1v;
      }
      Mg[r0+0][c0+0] = ((r0+0)==(c0+0) ? ccv[r0+0]+SREG : 0.0) - m00;
      Mg[r0+0][c0+1] = ((r0+0)==(c0+1) ? ccv[r0+0]+SREG : 0.0) - m01;
      Mg[r0+1][c0+0] = ((r0+1)==(c0+0) ? ccv[r0+1]+SREG : 0.0) - m10;
      Mg[r0+1][c0+1] = ((r0+1)==(c0+1) ? ccv[r0+1]+SREG : 0.0) - m11;
      Mg[r0+2][c0+0] = ((r0+2)==(c0+0) ? ccv[r0+2]+SREG : 0.0) - m20;
      Mg[r0+2][c0+1] = ((r0+2)==(c0+1) ? ccv[r0+2]+SREG : 0.0) - m21;
      Mg[r0+3][c0+0] = ((r0+3)==(c0+0) ? ccv[r0+3]+SREG : 0.0) - m30;
      Mg[r0+3][c0+1] = ((r0+3)==(c0+1) ? ccv[r0+3]+SREG : 0.0) - m31;
    } else if (tid < 400) {
      // border columns 64 (rhs_d) / 65 (mw): 128 serial dots of length 64
      const int d = tid - 272;
      const int j = d & 63, cc = d >> 6;
      double acc = 0.0;
#pragma unroll 8
      for (int i = 0; i < 64; ++i) {
        double vv = cc ? usv[i] : rsv[i];
        acc += DnT[j][i] * vv;
      }
      if (cc == 0) Mg[j][64] = rhs2v[j] - acc;
      else { double vv2 = wvv[j] - acc; Mg[j][65] = vv2; mw0[j] = vv2; }
    }
    __syncthreads();

    // ---- mirror lower triangle; wave 0 also inverts panel-0 pivot --------
    if (w == 0) {
      // pivot-block pairs: idx 0..119 (j<16)
#pragma unroll
      for (int e = 0; e < 2; ++e) {
        int idx = 2 * lane + e;
        if (idx < 120) { int j, l; pair_jl(idx, j, l); Mg[j][l] = Mg[l][j]; }
      }
      F1_INVERT(0);                    // wave-lockstep: sees own wave's writes
    } else {
      const int wtid = tid - 64;
#pragma unroll
      for (int r = 0; r < 5; ++r) {
        int idx = 120 + wtid + 448 * r;
        if (idx < 2016) { int j, l; pair_jl(idx, j, l); Mg[j][l] = Mg[l][j]; }
      }
    }
    __syncthreads();

    // ---- Phase F: block Gauss-Jordan, 4 panels; F1(next) hidden in F3 ----
#pragma unroll
    for (int pk = 0; pk < 4; ++pk) {
      const int k0   = 16 * pk;
      const int rest = 50 - k0;        // 50, 34, 18, 2

      // -- F2: Pbuf = Binv * Mg[panel rows, rest cols] (all threads) ------
      for (int o = tid; o < 16 * rest; o += NT) {
        int t = o / rest, c = o - t * rest;
        double acc = 0.0;
#pragma unroll
        for (int s = 0; s < 16; ++s) acc += Binv[t][s] * Mg[k0 + s][k0 + 16 + c];
        Pbuf[t][c] = acc;
      }
      __syncthreads();

      // -- F3 phase -------------------------------------------------------
      if (pk < 3) {
        if (w == 0) {
          // update next pivot block (16x16), then invert it
#pragma unroll
          for (int e = 0; e < 4; ++e) {
            int idx = lane + 64 * e;                 // 0..255
            int r = k0 + 16 + (idx >> 4), c = (idx & 15);
            double acc = Mg[r][k0 + 16 + c];
#pragma unroll
            for (int t = 0; t < 16; ++t) acc -= Mg[r][k0 + t] * Pbuf[t][c];
            Mg[r][k0 + 16 + c] = acc;
          }
          F1_INVERT(k0 + 16);
        } else {
          const int wtid = tid - 64;
          for (int o = wtid; o < 48 * rest; o += 448) {
            int rr = o / rest, c = o - rr * rest;
            int r = rr < k0 ? rr : rr + 16;
            bool excl = (r >= k0 + 16) && (r < k0 + 32) && (c < 16);
            if (!excl) {
              double acc = Mg[r][k0 + 16 + c];
#pragma unroll
              for (int t = 0; t < 16; ++t) acc -= Mg[r][k0 + t] * Pbuf[t][c];
              Mg[r][k0 + 16 + c] = acc;
            }
          }
          for (int o = wtid; o < 16 * rest; o += 448) {
            int t = o / rest, c = o - t * rest;
            Mg[k0 + t][k0 + 16 + c] = Pbuf[t][c];
          }
        }
      } else {
        // last panel: rest=2, tiny — all threads
        for (int o = tid; o < 48 * rest; o += NT) {
          int rr = o / rest, c = o - rr * rest;
          int r = rr < k0 ? rr : rr + 16;
          double acc = Mg[r][k0 + 16 + c];
#pragma unroll
          for (int t = 0; t < 16; ++t) acc -= Mg[r][k0 + t] * Pbuf[t][c];
          Mg[r][k0 + 16 + c] = acc;
        }
        for (int o = tid; o < 16 * rest; o += NT) {
          int t = o / rest, c = o - t * rest;
          Mg[k0 + t][k0 + 16 + c] = Pbuf[t][c];
        }
      }
      __syncthreads();
    }

    // ---- Phase H: fairness border solve (redundant in every wave) --------
    double ddl, tf;
    {
      double qsum = 0.0, fg = 0.0, fzs = 0.0;
#pragma unroll
      for (int q = 0; q < 8; ++q) { qsum += wpQ[q]; fg += wpFg[q]; fzs += wpFz[q]; }
      double h1 = Mg[lane][64], h2 = Mg[lane][65];
      double a1 = wsum(usv[lane] * usv[lane]);
      double a2 = wsum(usv[lane] * rsv[lane]);
      double a3 = wsum(mw0[lane] * h1);
      double a4 = wsum(mw0[lane] * h2);
      double qp  = qsum + SREG - a1;
      double r3p = (fg + fzs) - a2;
      tf  = (r3p - a3) / (qp - a4);
      ddl = h1 - tf * h2;
    }

    // ---- Phase I: row duals (in-register), dz/ds/dlam, alpha -------------
    double dar[NCH];
    double bs = 0.0;          // s-side rate max
    double rl = BIGV;         // lambda-side ratio min
#pragma unroll
    for (int k = 0; k < NCH; ++k) {
      int i = w + 8 * k;
      double rdot = wsum(dinv[k] * ddl);
      double dv = (rhs1[i] - rdot - uvv[i] * tf) / Rhv[i];
      dar[k] = dv;
      double d   = (rz[k] - (dv + ddl + tf * fe[k])) * dinv[k];
      double ds1 = d - (s1[k] - z[k]);
      double ds2 = -(z[k] + s2[k] - 1.0) - d;
      bs = fmax(bs, fmax(-ds1 * is1[k], -ds2 * is2[k]));
      double dl1 = (-(l1[k] * s1[k] - mu01) - l1[k] * ds1) * is1[k];
      double dl2 = (-(l2[k] * s2[k] - mu01) - l2[k] * ds2) * is2[k];
      if (dl1 < 0.0) rl = fmin(rl, -l1[k] / dl1);
      if (dl2 < 0.0) rl = fmin(rl, -l2[k] / dl2);
    }
    bs = wmax(bs);
    rl = wmin(rl);
    if (lane == 0) { wpS[w] = bs; wpL[w] = rl; }
    __syncthreads();
    double al;
    {
      double bm = wpS[0], rm = wpL[0];
#pragma unroll
      for (int q = 1; q < 8; ++q) { bm = fmax(bm, wpS[q]); rm = fmin(rm, wpL[q]); }
      double a_s = bm > 0.0 ? 1.0 / bm : BIGV;
      al = fmin(1.0, 0.99 * fmin(a_s, rm));
    }

    // ---- update ----------------------------------------------------------
#pragma unroll
    for (int k = 0; k < NCH; ++k) {
      double d   = (rz[k] - (dar[k] + ddl + tf * fe[k])) * dinv[k];
      double ds1 = d - (s1[k] - z[k]);
      double ds2 = -(z[k] + s2[k] - 1.0) - d;
      double dl1 = (-(l1[k] * s1[k] - mu01) - l1[k] * ds1) * is1[k];
      double dl2 = (-(l2[k] * s2[k] - mu01) - l2[k] * ds2) * is2[k];
      z[k]  += al * d;
      s1[k] += al * ds1;
      s2[k] += al * ds2;
      l1[k] += al * dl1;
      l2[k] += al * dl2;
      if (lane == 0) yav[w + 8 * k] += al * dar[k];
    }
    if (tid < 64) ydv[tid] += al * ddl;
    if (tid == 0) scal[6] += al * tf;
    // no end barrier: Phase A's barrier orders these LDS writes before C's reads
  }

  // ---- output (fp32) ------------------------------------------------------
#pragma unroll
  for (int k = 0; k < NCH; ++k) {
    int e = tid + NT * k;
    outp[(size_t)b * NXX + e] = (float)z[k];
  }
}

extern "C" void kernel_launch(void* const* d_in, const int* in_sizes, int n_in,
                              void* d_out, int out_size, void* d_ws, size_t ws_size,
                              hipStream_t stream)
{
  const float* x   = (const float*)d_in[0];
  const float* gid = (const float*)d_in[1];
  const float* ex  = (const float*)d_in[2];
  float* out = (float*)d_out;
  int nb = in_sizes[0] / NXX;   // 32 batches
  hipLaunchKernelGGL(ipm_kernel, dim3(nb), dim3(NT), 0, stream, x, gid, ex, out);
}